// Round 1
// baseline (727.373 us; speedup 1.0000x reference)
//
#include <hip/hip_runtime.h>
#include <hip/hip_bf16.h>
#include <cmath>
#include <cstdint>

// Problem constants
#define B_   8
#define S_   1024
#define D_   512
#define H_   8
#define DK_  64
#define DFF_ 2048
#define MR_  (B_*S_)   // 8192 rows

typedef __attribute__((ext_vector_type(8))) __bf16 bf16x8;
typedef __attribute__((ext_vector_type(4))) float  f32x4;

__device__ inline f32x4 mfma16(bf16x8 a, bf16x8 b, f32x4 c) {
  return __builtin_amdgcn_mfma_f32_16x16x32_bf16(a, b, c, 0, 0, 0);
}

__device__ inline unsigned short f2bf(float x) {
  union { float f; unsigned u; } v; v.f = x;
  unsigned r = (v.u + 0x7fffu + ((v.u >> 16) & 1u)) >> 16;
  return (unsigned short)r;
}

// ---------------- elementwise f32 -> bf16 ----------------
__global__ void cvt_bf16_kernel(const float* __restrict__ in, unsigned short* __restrict__ out) {
  int i = blockIdx.x * blockDim.x + threadIdx.x;
  float4 v = ((const float4*)in)[i];
  ushort4 o;
  o.x = f2bf(v.x); o.y = f2bf(v.y); o.z = f2bf(v.z); o.w = f2bf(v.w);
  ((ushort4*)out)[i] = o;
}

// ---------------- transpose + convert: W (K x N) f32 -> Wt (N x K) bf16 ----------------
__global__ void tcvt_kernel(const float* __restrict__ W, unsigned short* __restrict__ Wt,
                            int K, int N) {
  __shared__ float t[32][33];
  int tx = threadIdx.x & 31, ty = threadIdx.x >> 5;   // 256 threads: 32 x 8
  int n0 = blockIdx.x * 32, k0 = blockIdx.y * 32;
  #pragma unroll
  for (int i = 0; i < 4; i++)
    t[ty + i * 8][tx] = W[(size_t)(k0 + ty + i * 8) * N + n0 + tx];
  __syncthreads();
  #pragma unroll
  for (int i = 0; i < 4; i++)
    Wt[(size_t)(n0 + ty + i * 8) * K + k0 + tx] = f2bf(t[tx][ty + i * 8]);
}

// ---------------- GEMM: C(MxN) = A(MxK,bf16) * Bt(NxK,bf16)^T with fused epilogues ----------------
enum { MODE_QKV = 0, MODE_OUT = 1, MODE_FF1 = 2, MODE_FF2 = 3 };

template<int MODE>
__launch_bounds__(256)
__global__ void gemm_kernel(const unsigned short* __restrict__ A,
                            const unsigned short* __restrict__ Bt,
                            int M, int N, int K,
                            const float* __restrict__ e0,
                            const float* __restrict__ e1,
                            void* __restrict__ p0,
                            void* __restrict__ p1,
                            void* __restrict__ p2) {
  __shared__ unsigned short Al[128][72];
  __shared__ unsigned short Bl[128][72];
  const int tid = threadIdx.x;
  const int lane = tid & 63, wid = tid >> 6;
  const int l15 = lane & 15, g = lane >> 4;
  const int wr = wid >> 1, wc = wid & 1;
  const int m0 = blockIdx.y * 128, n0 = blockIdx.x * 128;

  const f32x4 fzero = {0.f, 0.f, 0.f, 0.f};
  f32x4 acc[4][4];
  #pragma unroll
  for (int i = 0; i < 4; i++)
    #pragma unroll
    for (int j = 0; j < 4; j++) acc[i][j] = fzero;

  for (int k0 = 0; k0 < K; k0 += 64) {
    #pragma unroll
    for (int i = 0; i < 4; i++) {
      int c = tid + 256 * i;               // 0..1023
      int row = c >> 3, ch = c & 7;        // 128 rows x 8 chunks of 16B
      *(uint4*)(&Al[row][ch * 8]) = *(const uint4*)(A  + (size_t)(m0 + row) * K + k0 + ch * 8);
      *(uint4*)(&Bl[row][ch * 8]) = *(const uint4*)(Bt + (size_t)(n0 + row) * K + k0 + ch * 8);
    }
    __syncthreads();
    #pragma unroll
    for (int kk = 0; kk < 2; kk++) {
      bf16x8 af[4], bfr[4];
      #pragma unroll
      for (int mi = 0; mi < 4; mi++)
        af[mi] = *(const bf16x8*)(&Al[wr * 64 + mi * 16 + l15][kk * 32 + g * 8]);
      #pragma unroll
      for (int ni = 0; ni < 4; ni++)
        bfr[ni] = *(const bf16x8*)(&Bl[wc * 64 + ni * 16 + l15][kk * 32 + g * 8]);
      #pragma unroll
      for (int mi = 0; mi < 4; mi++)
        #pragma unroll
        for (int ni = 0; ni < 4; ni++)
          acc[mi][ni] = mfma16(af[mi], bfr[ni], acc[mi][ni]);
    }
    __syncthreads();
  }

  // Epilogue: C[row][col], row = m0+wr*64+mi*16+g*4+r, col = n0+wc*64+ni*16+l15
  #pragma unroll
  for (int mi = 0; mi < 4; mi++) {
    #pragma unroll
    for (int ni = 0; ni < 4; ni++) {
      int row0 = m0 + wr * 64 + mi * 16 + g * 4;
      int col  = n0 + wc * 64 + ni * 16 + l15;
      if constexpr (MODE == MODE_QKV) {
        int which = n0 >> 9;  // block-uniform: 0=q, 1=k, 2=v
        if (which < 2) {
          unsigned short* dst = (unsigned short*)(which == 0 ? p0 : p1);
          int cw = col - which * 512;
          int h = cw >> 6, dk = cw & 63;
          #pragma unroll
          for (int r = 0; r < 4; r++) {
            int row = row0 + r; int b = row >> 10, s = row & 1023;
            dst[(((size_t)(b * 8 + h) * 1024 + s) << 6) + dk] = f2bf(acc[mi][ni][r]);
          }
        } else {
          unsigned short* vt = (unsigned short*)p2;   // (B,H,DK,S)
          int cw = col - 1024;
          int h = cw >> 6, dk = cw & 63;
          int b = row0 >> 10, s = row0 & 1023;        // r=0..3 are consecutive s
          ushort4 o;
          o.x = f2bf(acc[mi][ni][0]); o.y = f2bf(acc[mi][ni][1]);
          o.z = f2bf(acc[mi][ni][2]); o.w = f2bf(acc[mi][ni][3]);
          *(ushort4*)(vt + ((size_t)(b * 8 + h) * 64 + dk) * 1024 + s) = o;
        }
      } else if constexpr (MODE == MODE_OUT) {
        float* xpre = (float*)p0;
        #pragma unroll
        for (int r = 0; r < 4; r++) {
          size_t idx = (size_t)(row0 + r) * 512 + col;
          xpre[idx] = acc[mi][ni][r] + e0[idx];       // + src residual
        }
      } else if constexpr (MODE == MODE_FF1) {
        unsigned short* h1 = (unsigned short*)p0;
        float bias = e0[col];
        #pragma unroll
        for (int r = 0; r < 4; r++) {
          float v = acc[mi][ni][r] + bias;
          v = 0.5f * v * (1.f + erff(v * 0.70710678118654752f));  // exact gelu
          h1[(size_t)(row0 + r) * 2048 + col] = f2bf(v);
        }
      } else {  // MODE_FF2
        float* ypre = (float*)p0;
        float bias = e0[col];
        #pragma unroll
        for (int r = 0; r < 4; r++) {
          size_t idx = (size_t)(row0 + r) * 512 + col;
          ypre[idx] = acc[mi][ni][r] + bias + e1[idx];  // + x residual
        }
      }
    }
  }
}

// ---------------- fused residual attention (flash-style, scores also emitted) ----------------
__launch_bounds__(256)
__global__ void attn_kernel(const unsigned short* __restrict__ q,   // (B,H,S,DK) bf16
                            const unsigned short* __restrict__ k,   // (B,H,S,DK) bf16
                            const unsigned short* __restrict__ vt,  // (B,H,DK,S) bf16
                            const float* __restrict__ prev,         // (B,H,S,S)
                            float* __restrict__ scores,             // (B,H,S,S) out
                            unsigned short* __restrict__ ctx) {     // (B,S,H*DK) bf16
  __shared__ unsigned short Kl[64][72];
  __shared__ unsigned short Vl[64][72];
  __shared__ unsigned short Pl[4][16][72];
  const int tid = threadIdx.x;
  const int lane = tid & 63, wid = tid >> 6;
  const int l15 = lane & 15, g = lane >> 4;
  const int bh = blockIdx.y;          // 0..63
  const int tile = blockIdx.x;        // 0..15
  const int sw = tile * 64 + wid * 16;  // wave's row base within head
  const f32x4 fzero = {0.f, 0.f, 0.f, 0.f};

  bf16x8 aq[2];
  #pragma unroll
  for (int c = 0; c < 2; c++)
    aq[c] = *(const bf16x8*)(q + ((size_t)bh * 1024 + sw + l15) * 64 + c * 32 + g * 8);

  f32x4 ctxa[4];
  #pragma unroll
  for (int i = 0; i < 4; i++) ctxa[i] = fzero;
  float m_run[4], l_run[4];
  #pragma unroll
  for (int r = 0; r < 4; r++) { m_run[r] = -INFINITY; l_run[r] = 0.f; }

  const float* pv = prev + ((size_t)bh << 20);
  float* so = scores + ((size_t)bh << 20);

  for (int kt = 0; kt < 16; kt++) {
    #pragma unroll
    for (int i = 0; i < 2; i++) {
      int c = tid + 256 * i;
      int row = c >> 3, ch = c & 7;
      *(uint4*)(&Kl[row][ch * 8]) = *(const uint4*)(k  + ((size_t)bh * 1024 + kt * 64 + row) * 64 + ch * 8);
      *(uint4*)(&Vl[row][ch * 8]) = *(const uint4*)(vt + ((size_t)bh * 64 + row) * 1024 + kt * 64 + ch * 8);
    }
    __syncthreads();

    // scores tile: 16 rows x 64 cols per wave
    f32x4 sc[4];
    #pragma unroll
    for (int f = 0; f < 4; f++) sc[f] = fzero;
    #pragma unroll
    for (int c = 0; c < 2; c++) {
      #pragma unroll
      for (int f = 0; f < 4; f++) {
        bf16x8 bk = *(const bf16x8*)(&Kl[f * 16 + l15][c * 32 + g * 8]);
        sc[f] = mfma16(aq[c], bk, sc[f]);
      }
    }
    // scale + prev, emit scores
    #pragma unroll
    for (int f = 0; f < 4; f++) {
      #pragma unroll
      for (int r = 0; r < 4; r++) {
        size_t idx = (size_t)(sw + g * 4 + r) * 1024 + kt * 64 + f * 16 + l15;
        float v = sc[f][r] * 0.125f + pv[idx];
        so[idx] = v;
        sc[f][r] = v;
      }
    }
    // online softmax (rows are wave-local; reduce over 16 lanes of same g)
    float alpha[4];
    #pragma unroll
    for (int r = 0; r < 4; r++) {
      float tm = fmaxf(fmaxf(sc[0][r], sc[1][r]), fmaxf(sc[2][r], sc[3][r]));
      #pragma unroll
      for (int m = 1; m < 16; m <<= 1) tm = fmaxf(tm, __shfl_xor(tm, m, 64));
      float mn = fmaxf(m_run[r], tm);
      alpha[r] = __expf(m_run[r] - mn);
      m_run[r] = mn;
    }
    #pragma unroll
    for (int f = 0; f < 4; f++)
      #pragma unroll
      for (int r = 0; r < 4; r++)
        sc[f][r] = __expf(sc[f][r] - m_run[r]);
    #pragma unroll
    for (int r = 0; r < 4; r++) {
      float rs = sc[0][r] + sc[1][r] + sc[2][r] + sc[3][r];
      #pragma unroll
      for (int m = 1; m < 16; m <<= 1) rs += __shfl_xor(rs, m, 64);
      l_run[r] = l_run[r] * alpha[r] + rs;
    }
    #pragma unroll
    for (int f = 0; f < 4; f++)
      #pragma unroll
      for (int r = 0; r < 4; r++) ctxa[f][r] *= alpha[r];

    // P -> LDS (C-layout to A-layout re-distribution)
    #pragma unroll
    for (int f = 0; f < 4; f++)
      #pragma unroll
      for (int r = 0; r < 4; r++)
        Pl[wid][g * 4 + r][f * 16 + l15] = f2bf(sc[f][r]);
    __syncthreads();

    // PV: ctx += P @ V
    #pragma unroll
    for (int c = 0; c < 2; c++) {
      bf16x8 pa = *(const bf16x8*)(&Pl[wid][l15][c * 32 + g * 8]);
      #pragma unroll
      for (int f2 = 0; f2 < 4; f2++) {
        bf16x8 bv = *(const bf16x8*)(&Vl[f2 * 16 + l15][c * 32 + g * 8]);
        ctxa[f2] = mfma16(pa, bv, ctxa[f2]);
      }
    }
    __syncthreads();
  }

  // epilogue: ctx/l, write (B,S,H*DK) bf16
  int b = bh >> 3, h = bh & 7;
  #pragma unroll
  for (int f2 = 0; f2 < 4; f2++) {
    #pragma unroll
    for (int r = 0; r < 4; r++) {
      float ov = ctxa[f2][r] / l_run[r];
      int s = sw + g * 4 + r;
      ctx[((size_t)(b * 1024 + s)) * 512 + h * 64 + f2 * 16 + l15] = f2bf(ov);
    }
  }
}

// ---------------- BatchNorm pieces ----------------
__global__ void bn_stats_kernel(const float* __restrict__ x, float* __restrict__ part) {
  int blk = blockIdx.x;   // 128 blocks x 64 rows
  int tid = threadIdx.x;  // 256
  float s0 = 0, s1 = 0, q0 = 0, q1 = 0;
  const float* xr = x + (size_t)blk * 64 * 512;
  for (int r = 0; r < 64; r++) {
    float a = xr[r * 512 + tid];
    float b = xr[r * 512 + tid + 256];
    s0 += a; q0 += a * a; s1 += b; q1 += b * b;
  }
  part[blk * 512 + tid] = s0;
  part[blk * 512 + tid + 256] = s1;
  part[65536 + blk * 512 + tid] = q0;
  part[65536 + blk * 512 + tid + 256] = q1;
}

__global__ void bn_finalize_kernel(const float* __restrict__ part,
                                   const float* __restrict__ w,
                                   const float* __restrict__ bb,
                                   float* __restrict__ ss) {
  int c = threadIdx.x;  // 512
  float s = 0, q = 0;
  for (int i = 0; i < 128; i++) { s += part[i * 512 + c]; q += part[65536 + i * 512 + c]; }
  float mean = s * (1.f / 8192.f);
  float var = q * (1.f / 8192.f) - mean * mean;
  float inv = rsqrtf(var + 1e-5f);
  float sc = w[c] * inv;
  ss[c] = sc;
  ss[512 + c] = bb[c] - mean * sc;
}

__global__ void bn_apply_kernel(const float* __restrict__ xpre, const float* __restrict__ ss,
                                float* __restrict__ xf, unsigned short* __restrict__ xb) {
  int i = blockIdx.x * blockDim.x + threadIdx.x;
  float4 v = ((const float4*)xpre)[i];
  int c0 = (i * 4) & 511;
  float4 o;
  o.x = v.x * ss[c0]     + ss[512 + c0];
  o.y = v.y * ss[c0 + 1] + ss[512 + c0 + 1];
  o.z = v.z * ss[c0 + 2] + ss[512 + c0 + 2];
  o.w = v.w * ss[c0 + 3] + ss[512 + c0 + 3];
  ((float4*)xf)[i] = o;
  if (xb) {
    ushort4 u; u.x = f2bf(o.x); u.y = f2bf(o.y); u.z = f2bf(o.z); u.w = f2bf(o.w);
    ((ushort4*)xb)[i] = u;
  }
}

// ---------------- launcher ----------------
extern "C" void kernel_launch(void* const* d_in, const int* in_sizes, int n_in,
                              void* d_out, int out_size, void* d_ws, size_t ws_size,
                              hipStream_t stream) {
  const float* src  = (const float*)d_in[0];
  const float* prev = (const float*)d_in[1];
  const float* Wq   = (const float*)d_in[2];
  const float* Wk   = (const float*)d_in[3];
  const float* Wv   = (const float*)d_in[4];
  const float* Wo   = (const float*)d_in[5];
  const float* bn1w = (const float*)d_in[6];
  const float* bn1b = (const float*)d_in[7];
  const float* W1   = (const float*)d_in[8];
  const float* b1   = (const float*)d_in[9];
  const float* W2   = (const float*)d_in[10];
  const float* b2   = (const float*)d_in[11];
  const float* bn2w = (const float*)d_in[12];
  const float* bn2b = (const float*)d_in[13];

  float* out_final = (float*)d_out;
  float* scores    = (float*)d_out + (size_t)B_ * S_ * D_;  // +4,194,304

  char* ws = (char*)d_ws;
  size_t off = 0;
  auto alloc = [&](size_t bytes) -> char* {
    char* p = ws + off;
    off = (off + bytes + 255) & ~(size_t)255;
    return p;
  };

  unsigned short* src_b  = (unsigned short*)alloc(8192ULL * 512 * 2);
  unsigned short* Wqkv_t = (unsigned short*)alloc(1536ULL * 512 * 2);
  unsigned short* Wo_t   = (unsigned short*)alloc(512ULL * 512 * 2);
  unsigned short* W1_t   = (unsigned short*)alloc(2048ULL * 512 * 2);
  unsigned short* W2_t   = (unsigned short*)alloc(512ULL * 2048 * 2);
  unsigned short* q_ws   = (unsigned short*)alloc(8192ULL * 512 * 2);
  unsigned short* k_ws   = (unsigned short*)alloc(8192ULL * 512 * 2);
  unsigned short* vt_ws  = (unsigned short*)alloc(8192ULL * 512 * 2);
  unsigned short* ctx_ws = (unsigned short*)alloc(8192ULL * 512 * 2);
  float* xpre = (float*)alloc(8192ULL * 512 * 4);
  float* xf   = (float*)alloc(8192ULL * 512 * 4);
  float* part = (float*)alloc(131072ULL * 4);
  float* ss   = (float*)alloc(2048ULL * 4);
  // lifetime aliases
  unsigned short* h1 = q_ws;    // 33.5MB spans q/k/vt/ctx (contiguous, all dead by FF1)
  unsigned short* xb = src_b;   // x bf16 over src_bf16 (dead after QKV gemm)
  float* ypre = xpre;           // over xpre (dead after bn1 apply)

  cvt_bf16_kernel<<<4096, 256, 0, stream>>>(src, src_b);
  tcvt_kernel<<<dim3(16, 16), 256, 0, stream>>>(Wq, Wqkv_t,              512, 512);
  tcvt_kernel<<<dim3(16, 16), 256, 0, stream>>>(Wk, Wqkv_t + 512 * 512,  512, 512);
  tcvt_kernel<<<dim3(16, 16), 256, 0, stream>>>(Wv, Wqkv_t + 1024 * 512, 512, 512);
  tcvt_kernel<<<dim3(16, 16), 256, 0, stream>>>(Wo, Wo_t, 512, 512);
  tcvt_kernel<<<dim3(64, 16), 256, 0, stream>>>(W1, W1_t, 512, 2048);
  tcvt_kernel<<<dim3(16, 64), 256, 0, stream>>>(W2, W2_t, 2048, 512);

  gemm_kernel<MODE_QKV><<<dim3(12, 64), 256, 0, stream>>>(
      src_b, Wqkv_t, 8192, 1536, 512, nullptr, nullptr, q_ws, k_ws, vt_ws);

  attn_kernel<<<dim3(16, 64), 256, 0, stream>>>(q_ws, k_ws, vt_ws, prev, scores, ctx_ws);

  gemm_kernel<MODE_OUT><<<dim3(4, 64), 256, 0, stream>>>(
      ctx_ws, Wo_t, 8192, 512, 512, src, nullptr, xpre, nullptr, nullptr);

  bn_stats_kernel<<<128, 256, 0, stream>>>(xpre, part);
  bn_finalize_kernel<<<1, 512, 0, stream>>>(part, bn1w, bn1b, ss);
  bn_apply_kernel<<<4096, 256, 0, stream>>>(xpre, ss, xf, xb);

  gemm_kernel<MODE_FF1><<<dim3(16, 64), 256, 0, stream>>>(
      xb, W1_t, 8192, 2048, 512, b1, nullptr, h1, nullptr, nullptr);

  gemm_kernel<MODE_FF2><<<dim3(4, 64), 256, 0, stream>>>(
      h1, W2_t, 8192, 512, 2048, b2, xf, ypre, nullptr, nullptr);

  bn_stats_kernel<<<128, 256, 0, stream>>>(ypre, part);
  bn_finalize_kernel<<<1, 512, 0, stream>>>(part, bn2w, bn2b, ss + 1024);
  bn_apply_kernel<<<4096, 256, 0, stream>>>(ypre, ss + 1024, out_final, nullptr);
}